// Round 5
// baseline (225.918 us; speedup 1.0000x reference)
//
#include <hip/hip_runtime.h>

typedef _Float16 f16x8 __attribute__((ext_vector_type(8)));
typedef float f32x4 __attribute__((ext_vector_type(4)));

#define EMB 768
#define LQ 128
#define LD 1024
#define NB 32

typedef const __attribute__((address_space(1))) char gas_char;
typedef __attribute__((address_space(3))) char las_char;

__device__ __forceinline__ void gload16(const void* g, void* l) {
    __builtin_amdgcn_global_load_lds((gas_char*)g, (las_char*)l, 16, 0, 0);
}

// 128B-row-stride tiles (BK=64 hw): 8 chunks of 16B, XOR row&7  (r2-proven)
#define SWZ(row, ch) ((row) * 64 + ((((ch) ^ ((row) & 7))) * 8))

// ---------- f32 -> f16, 8 elems/thread ----------
__global__ void cvt8_kernel(const float* __restrict__ in, _Float16* __restrict__ out, int n8) {
    int i = blockIdx.x * 256 + threadIdx.x;
    if (i >= n8) return;
    const float4 a = ((const float4*)in)[2 * i];
    const float4 b = ((const float4*)in)[2 * i + 1];
    f16x8 o;
    o[0] = (_Float16)a.x; o[1] = (_Float16)a.y; o[2] = (_Float16)a.z; o[3] = (_Float16)a.w;
    o[4] = (_Float16)b.x; o[5] = (_Float16)b.y; o[6] = (_Float16)b.z; o[7] = (_Float16)b.w;
    ((f16x8*)out)[i] = o;
}

// ---------- VT[b][e][q] = query_embed[b][q][e] (f16) ----------
__global__ void make_vt_kernel(const float* __restrict__ Q, _Float16* __restrict__ VT) {
    int i = blockIdx.x * 256 + threadIdx.x;
    if (i >= NB * EMB * LQ) return;
    int q = i % LQ;
    int e = (i / LQ) % EMB;
    int b = i / (LQ * EMB);
    VT[i] = (_Float16)Q[((size_t)b * LQ + q) * EMB + e];
}

// Stage a 128-row x 64-halfword f16 tile (global row stride = 768 halfwords).
__device__ __forceinline__ void stage_tile(const _Float16* g, _Float16* l, int wave, int lane) {
#pragma unroll
    for (int i = 0; i < 4; ++i) {
        const int idx = i * 256 + wave * 64 + lane;
        const int row = idx >> 3, ch = idx & 7;
        const int lch = ch ^ (row & 7);
        gload16(g + (size_t)row * EMB + lch * 8, l + (size_t)(i * 256 + wave * 64) * 8);
    }
}

// ---------- query projection (r2-proven 128x128 kernel) ----------
__global__ __launch_bounds__(256) void proj128_kernel(
    const _Float16* __restrict__ A, const _Float16* __restrict__ B,
    const float* __restrict__ bias, _Float16* __restrict__ OUT) {
    __shared__ __align__(16) _Float16 smem[32768];
    const int tid = threadIdx.x, wave = tid >> 6, lane = tid & 63;
    const int wr = wave >> 1, wc = wave & 1;
    const int lr = lane & 15, lkg = lane >> 4;
    const int row0 = blockIdx.x * 128, col0 = blockIdx.y * 128;
    const _Float16* ga = A + (size_t)row0 * EMB;
    const _Float16* gb = B + (size_t)col0 * EMB;

    f32x4 acc[4][4];
#pragma unroll
    for (int m = 0; m < 4; ++m)
#pragma unroll
        for (int n = 0; n < 4; ++n) acc[m][n] = (f32x4){0.f, 0.f, 0.f, 0.f};

    stage_tile(ga, smem, wave, lane);
    stage_tile(gb, smem + 8192, wave, lane);
    int cur = 0;
    for (int it = 0; it < 12; ++it) {
        __syncthreads();
        if (it < 11) {
            stage_tile(ga + (it + 1) * 64, smem + (cur ^ 1) * 16384, wave, lane);
            stage_tile(gb + (it + 1) * 64, smem + (cur ^ 1) * 16384 + 8192, wave, lane);
        }
        const _Float16* sA = smem + cur * 16384;
        const _Float16* sB = smem + cur * 16384 + 8192;
#pragma unroll
        for (int kk = 0; kk < 2; ++kk) {
            const int ch = kk * 4 + lkg;
            f16x8 af[4], bf[4];
#pragma unroll
            for (int m = 0; m < 4; ++m)
                af[m] = *(const f16x8*)(sA + SWZ(wr * 64 + m * 16 + lr, ch));
#pragma unroll
            for (int n = 0; n < 4; ++n)
                bf[n] = *(const f16x8*)(sB + SWZ(wc * 64 + n * 16 + lr, ch));
#pragma unroll
            for (int m = 0; m < 4; ++m)
#pragma unroll
                for (int n = 0; n < 4; ++n)
                    acc[m][n] = __builtin_amdgcn_mfma_f32_16x16x32_f16(af[m], bf[n], acc[m][n], 0, 0, 0);
        }
        cur ^= 1;
    }
    const int crow = lkg * 4;
#pragma unroll
    for (int n = 0; n < 4; ++n) {
        const int gc = col0 + wc * 64 + n * 16 + lr;
        const float bv = bias[gc];
#pragma unroll
        for (int m = 0; m < 4; ++m) {
            const size_t gr = row0 + wr * 64 + m * 16 + crow;
#pragma unroll
            for (int r = 0; r < 4; ++r) {
                float v = acc[m][n][r] + bv;
                OUT[(gr + r) * EMB + gc] = (_Float16)(v > 0.f ? v : 0.f);
            }
        }
    }
}

// W tile t (t = hc*12 + kt): rows hc*128..+127 of W16, cols kt*64..+63. SWZ layout.
__device__ __forceinline__ void stage_w(const _Float16* __restrict__ W16,
                                        _Float16* sWbuf, int t, int tid) {
    const int hc = t / 12, kt = t - hc * 12;
    const _Float16* gsrc = W16 + (size_t)hc * 128 * EMB + kt * 64;
#pragma unroll
    for (int ii = 0; ii < 4; ++ii) {
        const int idx = ii * 256 + tid;
        const int row = idx >> 3, ch = idx & 7;
        gload16(gsrc + (size_t)row * EMB + ((ch ^ (row & 7)) * 8), sWbuf + (size_t)idx * 8);
    }
}

// ---------- FUSED: doc(f32) -> proj+relu -> scores -> softmax -> PV -> out(f32) ----------
// Block = 64 doc rows (4 waves x 16 rows). doc A-fragments in registers (af[24], read
// doc exactly once); W streamed through double-buffered LDS (__syncthreads fencing —
// raw s_barrier raced in R4); scores accumulate in registers across 6 hidden-chunks;
// per-wave LDS transpose buffer turns proj C-frags into scores/PV A-frags.
__global__ __launch_bounds__(256, 2) void fused_kernel(
    const float* __restrict__ doc, const _Float16* __restrict__ W16,
    const float* __restrict__ bias, const _Float16* __restrict__ Qo,
    const _Float16* __restrict__ VT, float* __restrict__ OUT) {
    __shared__ __align__(16) _Float16 sW[2 * 8192];     // dbuf W chunks [128][64], SWZ
    __shared__ __align__(16) _Float16 doC[4][16][136];  // per-wave Do_c / P (pad->2-way)

    const int tid = threadIdx.x, wave = tid >> 6, lane = tid & 63;
    const int lr = lane & 15, lkg = lane >> 4;

    // XCD swizzle: xcd owns 4 batches -> Qo/VT L2-resident per XCD
    const int l = blockIdx.x;            // 0..511
    const int x = l & 7, i = l >> 3;
    const int b = x * 4 + (i >> 4), dblk = i & 15;

    stage_w(W16, sW, 0, tid);  // tile 0 -> buf 0

    // doc tile A-fragments: lane holds row (wave*16+lr), k-slice lkg*8 within each 32
    const float* drow = doc + ((size_t)b * LD + dblk * 64 + wave * 16 + lr) * EMB;
    f16x8 af[24];
#pragma unroll
    for (int k = 0; k < 24; ++k) {
        const float4 xa = *(const float4*)(drow + k * 32 + lkg * 8);
        const float4 xb = *(const float4*)(drow + k * 32 + lkg * 8 + 4);
        f16x8 v;
        v[0] = (_Float16)xa.x; v[1] = (_Float16)xa.y; v[2] = (_Float16)xa.z; v[3] = (_Float16)xa.w;
        v[4] = (_Float16)xb.x; v[5] = (_Float16)xb.y; v[6] = (_Float16)xb.z; v[7] = (_Float16)xb.w;
        af[k] = v;
    }

    f32x4 sc[8];  // scores: 16 rows x 128 q, accumulated across all hc
#pragma unroll
    for (int n = 0; n < 8; ++n) sc[n] = (f32x4){0.f, 0.f, 0.f, 0.f};

    const int crow = lkg * 4;

#pragma unroll 1
    for (int hc = 0; hc < 6; ++hc) {
        f32x4 a2[8];  // proj chunk acc: 16 rows x 128 h-cols
#pragma unroll
        for (int n = 0; n < 8; ++n) a2[n] = (f32x4){0.f, 0.f, 0.f, 0.f};

#pragma unroll 1
        for (int kt = 0; kt < 12; ++kt) {
            const int t = hc * 12 + kt;
            __syncthreads();  // tile t landed (vmcnt drain) + all waves done with buf (t+1)&1
            if (t < 71) stage_w(W16, sW + ((t + 1) & 1) * 8192, t + 1, tid);
            const _Float16* bw = sW + (t & 1) * 8192;
#pragma unroll
            for (int kk = 0; kk < 2; ++kk) {
#pragma unroll
                for (int n = 0; n < 8; ++n) {
                    const f16x8 bf = *(const f16x8*)(bw + SWZ(n * 16 + lr, kk * 4 + lkg));
                    a2[n] = __builtin_amdgcn_mfma_f32_16x16x32_f16(af[kt * 2 + kk], bf, a2[n], 0, 0, 0);
                }
            }
        }

        // epilogue: bias+relu -> per-wave transpose buffer (C-layout -> A-layout)
#pragma unroll
        for (int n = 0; n < 8; ++n) {
            const float bv = bias[hc * 128 + n * 16 + lr];
#pragma unroll
            for (int r = 0; r < 4; ++r) {
                float v = a2[n][r] + bv;
                doC[wave][crow + r][n * 16 + lr] = (_Float16)(v > 0.f ? v : 0.f);
            }
        }
        // scores: sc += Do_c[16,128h] . Qo[128q,128h]^T (B-frags direct from L2)
#pragma unroll
        for (int ks = 0; ks < 4; ++ks) {
            const f16x8 pa = *(const f16x8*)(&doC[wave][lr][ks * 32 + lkg * 8]);
#pragma unroll
            for (int n = 0; n < 8; ++n) {
                const f16x8 bq = *(const f16x8*)(Qo + ((size_t)b * LQ + n * 16 + lr) * EMB
                                                 + hc * 128 + ks * 32 + lkg * 8);
                sc[n] = __builtin_amdgcn_mfma_f32_16x16x32_f16(pa, bq, sc[n], 0, 0, 0);
            }
        }
    }

    // ---- softmax over 128 per doc row (16-lane-group shfl), P -> doC (reuse) ----
#pragma unroll
    for (int r = 0; r < 4; ++r) {
        float mx = -1e30f;
#pragma unroll
        for (int n = 0; n < 8; ++n) mx = fmaxf(mx, sc[n][r]);
#pragma unroll
        for (int off = 1; off < 16; off <<= 1) mx = fmaxf(mx, __shfl_xor(mx, off));
        float p[8], sum = 0.f;
#pragma unroll
        for (int n = 0; n < 8; ++n) { p[n] = __expf(sc[n][r] - mx); sum += p[n]; }
#pragma unroll
        for (int off = 1; off < 16; off <<= 1) sum += __shfl_xor(sum, off);
        const float inv = 1.f / sum;
#pragma unroll
        for (int n = 0; n < 8; ++n) doC[wave][crow + r][n * 16 + lr] = (_Float16)(p[n] * inv);
    }

    // ---- PV: out[16,768] per wave = P[16,128] . V ; VT[e][q] from L2 ----
    const _Float16* vtb = VT + (size_t)b * EMB * LQ;
    const size_t dbase = (size_t)b * LD + dblk * 64 + wave * 16 + crow;
#pragma unroll 1
    for (int nc = 0; nc < 6; ++nc) {
        f32x4 o[8];
#pragma unroll
        for (int t = 0; t < 8; ++t) o[t] = (f32x4){0.f, 0.f, 0.f, 0.f};
#pragma unroll
        for (int ks = 0; ks < 4; ++ks) {
            const f16x8 am = *(const f16x8*)(&doC[wave][lr][ks * 32 + lkg * 8]);
#pragma unroll
            for (int t = 0; t < 8; ++t) {
                const f16x8 bv = *(const f16x8*)(vtb + (size_t)(nc * 128 + t * 16 + lr) * LQ
                                                 + ks * 32 + lkg * 8);
                o[t] = __builtin_amdgcn_mfma_f32_16x16x32_f16(am, bv, o[t], 0, 0, 0);
            }
        }
#pragma unroll
        for (int t = 0; t < 8; ++t) {
            const int e = nc * 128 + t * 16 + lr;
#pragma unroll
            for (int r = 0; r < 4; ++r)
                OUT[(dbase + r) * EMB + e] = o[t][r];
        }
    }
}

extern "C" void kernel_launch(void* const* d_in, const int* in_sizes, int n_in,
                              void* d_out, int out_size, void* d_ws, size_t ws_size,
                              hipStream_t stream) {
    const float* doc   = (const float*)d_in[0];   // [32,1024,768]
    const float* query = (const float*)d_in[1];   // [32,128,768]
    const float* W     = (const float*)d_in[2];   // [768,768]
    const float* bias  = (const float*)d_in[3];   // [768]
    float* out = (float*)d_out;                   // [32,1024,768] f32

    const size_t nW  = (size_t)EMB * EMB;        // 589824
    const size_t nQ  = (size_t)NB * LQ * EMB;    // 3145728 (q16)
    const size_t nVT = (size_t)NB * EMB * LQ;    // 3145728
    const size_t nQo = (size_t)NB * LQ * EMB;    // 3145728
    const size_t need = (nW + nQ + nVT + nQo) * sizeof(_Float16);  // ~20 MB
    if (ws_size < need) return;

    _Float16* W16 = (_Float16*)d_ws;
    _Float16* q16 = W16 + nW;
    _Float16* VT  = q16 + nQ;
    _Float16* Qo  = VT + nVT;

    cvt8_kernel<<<(int)(nW / 8 / 256), 256, 0, stream>>>(W, W16, (int)(nW / 8));
    cvt8_kernel<<<(int)(nQ / 8 / 256), 256, 0, stream>>>(query, q16, (int)(nQ / 8));
    make_vt_kernel<<<(int)(nVT / 256), 256, 0, stream>>>(query, VT);

    // Qo = relu(query . W^T + b)  (M=4096)
    proj128_kernel<<<dim3(NB * LQ / 128, EMB / 128), 256, 0, stream>>>(q16, W16, bias, Qo);

    // fused doc pipeline: 512 blocks (32 batches x 16 blocks of 64 rows)
    fused_kernel<<<dim3(NB * 16), 256, 0, stream>>>(doc, W16, bias, Qo, VT, out);
}

// Round 6
// 204.980 us; speedup vs baseline: 1.1021x; 1.1021x over previous
//
#include <hip/hip_runtime.h>

typedef _Float16 f16x8 __attribute__((ext_vector_type(8)));
typedef float f32x4 __attribute__((ext_vector_type(4)));

#define EMB 768
#define LQ 128
#define LD 1024
#define NB 32

typedef const __attribute__((address_space(1))) char gas_char;
typedef __attribute__((address_space(3))) char las_char;

__device__ __forceinline__ void gload16(const void* g, void* l) {
    __builtin_amdgcn_global_load_lds((gas_char*)g, (las_char*)l, 16, 0, 0);
}

// 128B-row-stride tiles (BK=64 hw): 8 chunks of 16B, XOR row&7  (r2-proven)
#define SWZ(row, ch) ((row) * 64 + ((((ch) ^ ((row) & 7))) * 8))

// ---------- f32 -> f16, 8 elems/thread ----------
__global__ void cvt8_kernel(const float* __restrict__ in, _Float16* __restrict__ out, int n8) {
    int i = blockIdx.x * 256 + threadIdx.x;
    if (i >= n8) return;
    const float4 a = ((const float4*)in)[2 * i];
    const float4 b = ((const float4*)in)[2 * i + 1];
    f16x8 o;
    o[0] = (_Float16)a.x; o[1] = (_Float16)a.y; o[2] = (_Float16)a.z; o[3] = (_Float16)a.w;
    o[4] = (_Float16)b.x; o[5] = (_Float16)b.y; o[6] = (_Float16)b.z; o[7] = (_Float16)b.w;
    ((f16x8*)out)[i] = o;
}

// ---------- VT[b][e][q] = query_embed[b][q][e] (f16) ----------
__global__ void make_vt_kernel(const float* __restrict__ Q, _Float16* __restrict__ VT) {
    int i = blockIdx.x * 256 + threadIdx.x;
    if (i >= NB * EMB * LQ) return;
    int q = i % LQ;
    int e = (i / LQ) % EMB;
    int b = i / (LQ * EMB);
    VT[i] = (_Float16)Q[((size_t)b * LQ + q) * EMB + e];
}

// Stage a 128-row x 64-halfword f16 tile (global row stride = 768 halfwords).
__device__ __forceinline__ void stage_tile(const _Float16* g, _Float16* l, int wave, int lane) {
#pragma unroll
    for (int i = 0; i < 4; ++i) {
        const int idx = i * 256 + wave * 64 + lane;
        const int row = idx >> 3, ch = idx & 7;
        const int lch = ch ^ (row & 7);
        gload16(g + (size_t)row * EMB + lch * 8, l + (size_t)(i * 256 + wave * 64) * 8);
    }
}

// ---------- query projection (r2-proven 128x128 kernel) ----------
__global__ __launch_bounds__(256) void proj128_kernel(
    const _Float16* __restrict__ A, const _Float16* __restrict__ B,
    const float* __restrict__ bias, _Float16* __restrict__ OUT) {
    __shared__ __align__(16) _Float16 smem[32768];
    const int tid = threadIdx.x, wave = tid >> 6, lane = tid & 63;
    const int wr = wave >> 1, wc = wave & 1;
    const int lr = lane & 15, lkg = lane >> 4;
    const int row0 = blockIdx.x * 128, col0 = blockIdx.y * 128;
    const _Float16* ga = A + (size_t)row0 * EMB;
    const _Float16* gb = B + (size_t)col0 * EMB;

    f32x4 acc[4][4];
#pragma unroll
    for (int m = 0; m < 4; ++m)
#pragma unroll
        for (int n = 0; n < 4; ++n) acc[m][n] = (f32x4){0.f, 0.f, 0.f, 0.f};

    stage_tile(ga, smem, wave, lane);
    stage_tile(gb, smem + 8192, wave, lane);
    int cur = 0;
    for (int it = 0; it < 12; ++it) {
        __syncthreads();
        if (it < 11) {
            stage_tile(ga + (it + 1) * 64, smem + (cur ^ 1) * 16384, wave, lane);
            stage_tile(gb + (it + 1) * 64, smem + (cur ^ 1) * 16384 + 8192, wave, lane);
        }
        const _Float16* sA = smem + cur * 16384;
        const _Float16* sB = smem + cur * 16384 + 8192;
#pragma unroll
        for (int kk = 0; kk < 2; ++kk) {
            const int ch = kk * 4 + lkg;
            f16x8 af[4], bf[4];
#pragma unroll
            for (int m = 0; m < 4; ++m)
                af[m] = *(const f16x8*)(sA + SWZ(wr * 64 + m * 16 + lr, ch));
#pragma unroll
            for (int n = 0; n < 4; ++n)
                bf[n] = *(const f16x8*)(sB + SWZ(wc * 64 + n * 16 + lr, ch));
#pragma unroll
            for (int m = 0; m < 4; ++m)
#pragma unroll
                for (int n = 0; n < 4; ++n)
                    acc[m][n] = __builtin_amdgcn_mfma_f32_16x16x32_f16(af[m], bf[n], acc[m][n], 0, 0, 0);
        }
        cur ^= 1;
    }
    const int crow = lkg * 4;
#pragma unroll
    for (int n = 0; n < 4; ++n) {
        const int gc = col0 + wc * 64 + n * 16 + lr;
        const float bv = bias[gc];
#pragma unroll
        for (int m = 0; m < 4; ++m) {
            const size_t gr = row0 + wr * 64 + m * 16 + crow;
#pragma unroll
            for (int r = 0; r < 4; ++r) {
                float v = acc[m][n][r] + bv;
                OUT[(gr + r) * EMB + gc] = (_Float16)(v > 0.f ? v : 0.f);
            }
        }
    }
}

// W tile (hc, kt): rows hc*128..+127 of W16, cols kt*64..+63. SWZ layout.
__device__ __forceinline__ void stage_w(const _Float16* __restrict__ W16,
                                        _Float16* sWbuf, int hc, int kt, int tid) {
    const _Float16* gsrc = W16 + (size_t)hc * 128 * EMB + kt * 64;
#pragma unroll
    for (int ii = 0; ii < 4; ++ii) {
        const int idx = ii * 256 + tid;
        const int row = idx >> 3, ch = idx & 7;
        gload16(gsrc + (size_t)row * EMB + ((ch ^ (row & 7)) * 8), sWbuf + (size_t)idx * 8);
    }
}

// ---------- FUSED: doc(f32) -> proj+relu -> scores -> softmax -> PV -> out(f32) ----------
// Block = 64 doc rows (4 waves x 16 rows). doc A-fragments in REGISTERS (af[24]; kt
// loop FULLY unrolled so af indexing is static — runtime indexing spilled to scratch
// in R5, VGPR_Count=68 + 90MB scratch traffic). W double-buffered via gload_lds with
// __syncthreads fencing (raw s_barrier raced in R4). Scores accumulate in registers
// across 6 hidden-chunks; per-wave LDS buffer transposes proj C-frags -> A-frags.
__global__ __launch_bounds__(256, 2) void fused_kernel(
    const float* __restrict__ doc, const _Float16* __restrict__ W16,
    const float* __restrict__ bias, const _Float16* __restrict__ Qo,
    const _Float16* __restrict__ VT, float* __restrict__ OUT) {
    __shared__ __align__(16) _Float16 sW[2 * 8192];     // dbuf W chunks [128][64], SWZ
    __shared__ __align__(16) _Float16 doC[4][16][136];  // per-wave Do_c / P (pad->2-way)

    const int tid = threadIdx.x, wave = tid >> 6, lane = tid & 63;
    const int lr = lane & 15, lkg = lane >> 4;

    // XCD swizzle: xcd owns 4 batches -> Qo/VT L2-resident per XCD
    const int l = blockIdx.x;            // 0..511
    const int x = l & 7, i = l >> 3;
    const int b = x * 4 + (i >> 4), dblk = i & 15;

    stage_w(W16, sW, 0, 0, tid);  // tile 0 -> buf 0

    // doc tile A-fragments: lane holds row (wave*16+lr), k-slice lkg*8 within each 32
    const float* drow = doc + ((size_t)b * LD + dblk * 64 + wave * 16 + lr) * EMB;
    f16x8 af[24];
#pragma unroll
    for (int k = 0; k < 24; ++k) {
        const float4 xa = *(const float4*)(drow + k * 32 + lkg * 8);
        const float4 xb = *(const float4*)(drow + k * 32 + lkg * 8 + 4);
        f16x8 v;
        v[0] = (_Float16)xa.x; v[1] = (_Float16)xa.y; v[2] = (_Float16)xa.z; v[3] = (_Float16)xa.w;
        v[4] = (_Float16)xb.x; v[5] = (_Float16)xb.y; v[6] = (_Float16)xb.z; v[7] = (_Float16)xb.w;
        af[k] = v;
    }

    f32x4 sc[8];  // scores: 16 rows x 128 q, accumulated across all hc
#pragma unroll
    for (int n = 0; n < 8; ++n) sc[n] = (f32x4){0.f, 0.f, 0.f, 0.f};

    const int crow = lkg * 4;

#pragma unroll 1
    for (int hc = 0; hc < 6; ++hc) {
        f32x4 a2[8];  // proj chunk acc: 16 rows x 128 h-cols
#pragma unroll
        for (int n = 0; n < 8; ++n) a2[n] = (f32x4){0.f, 0.f, 0.f, 0.f};

#pragma unroll  // FULL unroll: af[] statically indexed (registers, not scratch)
        for (int kt = 0; kt < 12; ++kt) {
            __syncthreads();  // tile (hc,kt) landed + all waves done with other buf
            if (kt < 11)      stage_w(W16, sW + ((kt + 1) & 1) * 8192, hc, kt + 1, tid);
            else if (hc < 5)  stage_w(W16, sW + ((kt + 1) & 1) * 8192, hc + 1, 0, tid);
            const _Float16* bw = sW + (kt & 1) * 8192;
#pragma unroll
            for (int kk = 0; kk < 2; ++kk) {
#pragma unroll
                for (int n = 0; n < 8; ++n) {
                    const f16x8 bf = *(const f16x8*)(bw + SWZ(n * 16 + lr, kk * 4 + lkg));
                    a2[n] = __builtin_amdgcn_mfma_f32_16x16x32_f16(af[kt * 2 + kk], bf, a2[n], 0, 0, 0);
                }
            }
        }

        // epilogue: bias+relu -> per-wave transpose buffer (C-layout -> A-layout)
#pragma unroll
        for (int n = 0; n < 8; ++n) {
            const float bv = bias[hc * 128 + n * 16 + lr];
#pragma unroll
            for (int r = 0; r < 4; ++r) {
                float v = a2[n][r] + bv;
                doC[wave][crow + r][n * 16 + lr] = (_Float16)(v > 0.f ? v : 0.f);
            }
        }
        // scores: sc += Do_c[16,128h] . Qo[128q,128h]^T (B-frags direct from L2)
#pragma unroll
        for (int ks = 0; ks < 4; ++ks) {
            const f16x8 pa = *(const f16x8*)(&doC[wave][lr][ks * 32 + lkg * 8]);
#pragma unroll
            for (int n = 0; n < 8; ++n) {
                const f16x8 bq = *(const f16x8*)(Qo + ((size_t)b * LQ + n * 16 + lr) * EMB
                                                 + hc * 128 + ks * 32 + lkg * 8);
                sc[n] = __builtin_amdgcn_mfma_f32_16x16x32_f16(pa, bq, sc[n], 0, 0, 0);
            }
        }
    }

    // ---- softmax over 128 per doc row (16-lane-group shfl), P -> doC (reuse) ----
#pragma unroll
    for (int r = 0; r < 4; ++r) {
        float mx = -1e30f;
#pragma unroll
        for (int n = 0; n < 8; ++n) mx = fmaxf(mx, sc[n][r]);
#pragma unroll
        for (int off = 1; off < 16; off <<= 1) mx = fmaxf(mx, __shfl_xor(mx, off));
        float p[8], sum = 0.f;
#pragma unroll
        for (int n = 0; n < 8; ++n) { p[n] = __expf(sc[n][r] - mx); sum += p[n]; }
#pragma unroll
        for (int off = 1; off < 16; off <<= 1) sum += __shfl_xor(sum, off);
        const float inv = 1.f / sum;
#pragma unroll
        for (int n = 0; n < 8; ++n) doC[wave][crow + r][n * 16 + lr] = (_Float16)(p[n] * inv);
    }

    // ---- PV: out[16,768] per wave = P[16,128] . V ; VT[e][q] from L2 ----
    const _Float16* vtb = VT + (size_t)b * EMB * LQ;
    const size_t dbase = (size_t)b * LD + dblk * 64 + wave * 16 + crow;
#pragma unroll 1
    for (int nc = 0; nc < 6; ++nc) {
        f32x4 o[8];
#pragma unroll
        for (int t = 0; t < 8; ++t) o[t] = (f32x4){0.f, 0.f, 0.f, 0.f};
#pragma unroll
        for (int ks = 0; ks < 4; ++ks) {
            const f16x8 am = *(const f16x8*)(&doC[wave][lr][ks * 32 + lkg * 8]);
#pragma unroll
            for (int t = 0; t < 8; ++t) {
                const f16x8 bv = *(const f16x8*)(vtb + (size_t)(nc * 128 + t * 16 + lr) * LQ
                                                 + ks * 32 + lkg * 8);
                o[t] = __builtin_amdgcn_mfma_f32_16x16x32_f16(am, bv, o[t], 0, 0, 0);
            }
        }
#pragma unroll
        for (int t = 0; t < 8; ++t) {
            const int e = nc * 128 + t * 16 + lr;
#pragma unroll
            for (int r = 0; r < 4; ++r)
                OUT[(dbase + r) * EMB + e] = o[t][r];
        }
    }
}

extern "C" void kernel_launch(void* const* d_in, const int* in_sizes, int n_in,
                              void* d_out, int out_size, void* d_ws, size_t ws_size,
                              hipStream_t stream) {
    const float* doc   = (const float*)d_in[0];   // [32,1024,768]
    const float* query = (const float*)d_in[1];   // [32,128,768]
    const float* W     = (const float*)d_in[2];   // [768,768]
    const float* bias  = (const float*)d_in[3];   // [768]
    float* out = (float*)d_out;                   // [32,1024,768] f32

    const size_t nW  = (size_t)EMB * EMB;        // 589824
    const size_t nQ  = (size_t)NB * LQ * EMB;    // 3145728 (q16)
    const size_t nVT = (size_t)NB * EMB * LQ;    // 3145728
    const size_t nQo = (size_t)NB * LQ * EMB;    // 3145728
    const size_t need = (nW + nQ + nVT + nQo) * sizeof(_Float16);  // ~20 MB
    if (ws_size < need) return;

    _Float16* W16 = (_Float16*)d_ws;
    _Float16* q16 = W16 + nW;
    _Float16* VT  = q16 + nQ;
    _Float16* Qo  = VT + nVT;

    cvt8_kernel<<<(int)(nW / 8 / 256), 256, 0, stream>>>(W, W16, (int)(nW / 8));
    cvt8_kernel<<<(int)(nQ / 8 / 256), 256, 0, stream>>>(query, q16, (int)(nQ / 8));
    make_vt_kernel<<<(int)(nVT / 256), 256, 0, stream>>>(query, VT);

    // Qo = relu(query . W^T + b)  (M=4096)
    proj128_kernel<<<dim3(NB * LQ / 128, EMB / 128), 256, 0, stream>>>(q16, W16, bias, Qo);

    // fused doc pipeline: 512 blocks (32 batches x 16 blocks of 64 rows)
    fused_kernel<<<dim3(NB * 16), 256, 0, stream>>>(doc, W16, bias, Qo, VT, out);
}

// Round 7
// 179.228 us; speedup vs baseline: 1.2605x; 1.1437x over previous
//
#include <hip/hip_runtime.h>

typedef _Float16 f16x8 __attribute__((ext_vector_type(8)));
typedef float f32x4 __attribute__((ext_vector_type(4)));

#define EMB 768
#define LQ 128
#define LD 1024
#define NB 32

typedef const __attribute__((address_space(1))) char gas_char;
typedef __attribute__((address_space(3))) char las_char;

__device__ __forceinline__ void gload16(const void* g, void* l) {
    __builtin_amdgcn_global_load_lds((gas_char*)g, (las_char*)l, 16, 0, 0);
}

// 128B-row-stride tiles (BK=64 hw): 8 chunks of 16B, XOR row&7  (r2-proven)
#define SWZ(row, ch) ((row) * 64 + ((((ch) ^ ((row) & 7))) * 8))

// ---------- f32 -> f16, 8 elems/thread (W only) ----------
__global__ void cvt8_kernel(const float* __restrict__ in, _Float16* __restrict__ out, int n8) {
    int i = blockIdx.x * 256 + threadIdx.x;
    if (i >= n8) return;
    const float4 a = ((const float4*)in)[2 * i];
    const float4 b = ((const float4*)in)[2 * i + 1];
    f16x8 o;
    o[0] = (_Float16)a.x; o[1] = (_Float16)a.y; o[2] = (_Float16)a.z; o[3] = (_Float16)a.w;
    o[4] = (_Float16)b.x; o[5] = (_Float16)b.y; o[6] = (_Float16)b.z; o[7] = (_Float16)b.w;
    ((f16x8*)out)[i] = o;
}

// ---------- VT[b][e][q] = query_embed[b][q][e] (f16) ----------
__global__ void make_vt_kernel(const float* __restrict__ Q, _Float16* __restrict__ VT) {
    int i = blockIdx.x * 256 + threadIdx.x;
    if (i >= NB * EMB * LQ) return;
    int q = i % LQ;
    int e = (i / LQ) % EMB;
    int b = i / (LQ * EMB);
    VT[i] = (_Float16)Q[((size_t)b * LQ + q) * EMB + e];
}

// Stage a 128-row x 64-halfword f16 tile from f16 global (row stride 768 hw).
__device__ __forceinline__ void stage_tile(const _Float16* g, _Float16* l, int tid) {
#pragma unroll
    for (int i = 0; i < 4; ++i) {
        const int idx = i * 256 + tid;
        const int row = idx >> 3, ch = idx & 7;
        gload16(g + (size_t)row * EMB + ((ch ^ (row & 7)) * 8), l + (size_t)idx * 8);
    }
}

// ---------- projection GEMM, A read DIRECTLY as f32 (reg-staged), B(W16) via gload_lds ----
// OUT[m,h] = relu(A[m,:] . W[h,:] + bias[h]) in f16. 128x128 tile, 4 waves, dbuf LDS,
// __syncthreads fencing (r2-proven loop shape). A-stage: issue f32 loads right after
// the barrier, cvt+ds_write AFTER the MFMA cluster (HBM latency hides under compute).
__global__ __launch_bounds__(256) void projd_kernel(
    const float* __restrict__ A, const _Float16* __restrict__ W16,
    const float* __restrict__ bias, _Float16* __restrict__ OUT) {
    __shared__ __align__(16) _Float16 smem[32768];  // 2 x (A 8192 | B 8192) halfwords
    const int tid = threadIdx.x, wave = tid >> 6, lane = tid & 63;
    const int wr = wave >> 1, wc = wave & 1;
    const int lr = lane & 15, lkg = lane >> 4;
    const int row0 = blockIdx.x * 128, col0 = blockIdx.y * 128;
    const float* ga = A + (size_t)row0 * EMB;
    const _Float16* gb = W16 + (size_t)col0 * EMB;

    // A-stage source coordinates: 4 chunks/thread, chunk idx -> (row, swizzled col)
    int srow[4], scol[4];
#pragma unroll
    for (int i = 0; i < 4; ++i) {
        const int idx = i * 256 + tid;
        srow[i] = idx >> 3;
        scol[i] = ((idx & 7) ^ (srow[i] & 7)) * 8;
    }

    f32x4 acc[4][4];
#pragma unroll
    for (int m = 0; m < 4; ++m)
#pragma unroll
        for (int n = 0; n < 4; ++n) acc[m][n] = (f32x4){0.f, 0.f, 0.f, 0.f};

    // prologue: A0 load+cvt+write, B0 gload_lds
    float4 areg[4][2];
#pragma unroll
    for (int i = 0; i < 4; ++i) {
        const float* src = ga + (size_t)srow[i] * EMB + scol[i];
        areg[i][0] = *(const float4*)(src);
        areg[i][1] = *(const float4*)(src + 4);
    }
    stage_tile(gb, smem + 8192, tid);
#pragma unroll
    for (int i = 0; i < 4; ++i) {
        f16x8 v;
        v[0] = (_Float16)areg[i][0].x; v[1] = (_Float16)areg[i][0].y;
        v[2] = (_Float16)areg[i][0].z; v[3] = (_Float16)areg[i][0].w;
        v[4] = (_Float16)areg[i][1].x; v[5] = (_Float16)areg[i][1].y;
        v[6] = (_Float16)areg[i][1].z; v[7] = (_Float16)areg[i][1].w;
        *(f16x8*)(smem + (size_t)(i * 256 + tid) * 8) = v;
    }

    int cur = 0;
    for (int it = 0; it < 12; ++it) {
        __syncthreads();  // B(it) landed (vmcnt) + A(it) ds_writes visible (lgkm) + buf^1 free
        if (it < 11) {
            // issue next A-tile f32 loads NOW (latency hides under MFMA below)
#pragma unroll
            for (int i = 0; i < 4; ++i) {
                const float* src = ga + (size_t)srow[i] * EMB + (it + 1) * 64 + scol[i];
                areg[i][0] = *(const float4*)(src);
                areg[i][1] = *(const float4*)(src + 4);
            }
            stage_tile(gb + (it + 1) * 64, smem + (cur ^ 1) * 16384 + 8192, tid);
        }
        const _Float16* sA = smem + cur * 16384;
        const _Float16* sB = sA + 8192;
#pragma unroll
        for (int kk = 0; kk < 2; ++kk) {
            const int ch = kk * 4 + lkg;
            f16x8 af[4], bf[4];
#pragma unroll
            for (int m = 0; m < 4; ++m)
                af[m] = *(const f16x8*)(sA + SWZ(wr * 64 + m * 16 + lr, ch));
#pragma unroll
            for (int n = 0; n < 4; ++n)
                bf[n] = *(const f16x8*)(sB + SWZ(wc * 64 + n * 16 + lr, ch));
#pragma unroll
            for (int m = 0; m < 4; ++m)
#pragma unroll
                for (int n = 0; n < 4; ++n)
                    acc[m][n] = __builtin_amdgcn_mfma_f32_16x16x32_f16(af[m], bf[n], acc[m][n], 0, 0, 0);
        }
        if (it < 11) {
            // cvt + write next A-tile into the other buffer (readers of it are done:
            // they passed the barrier above; next barrier orders these writes)
            _Float16* dst = smem + (cur ^ 1) * 16384;
#pragma unroll
            for (int i = 0; i < 4; ++i) {
                f16x8 v;
                v[0] = (_Float16)areg[i][0].x; v[1] = (_Float16)areg[i][0].y;
                v[2] = (_Float16)areg[i][0].z; v[3] = (_Float16)areg[i][0].w;
                v[4] = (_Float16)areg[i][1].x; v[5] = (_Float16)areg[i][1].y;
                v[6] = (_Float16)areg[i][1].z; v[7] = (_Float16)areg[i][1].w;
                *(f16x8*)(dst + (size_t)(i * 256 + tid) * 8) = v;
            }
        }
        cur ^= 1;
    }

    const int crow = lkg * 4;
#pragma unroll
    for (int n = 0; n < 4; ++n) {
        const int gc = col0 + wc * 64 + n * 16 + lr;
        const float bv = bias[gc];
#pragma unroll
        for (int m = 0; m < 4; ++m) {
            const size_t gr = row0 + wr * 64 + m * 16 + crow;
#pragma unroll
            for (int r = 0; r < 4; ++r) {
                float v = acc[m][n][r] + bv;
                OUT[(gr + r) * EMB + gc] = (_Float16)(v > 0.f ? v : 0.f);
            }
        }
    }
}

// ---------- attention: 128 doc rows/block (r2-proven, verbatim) ----------
__global__ __launch_bounds__(256) void attn128_kernel(
    const _Float16* __restrict__ Do, const _Float16* __restrict__ Qo,
    const _Float16* __restrict__ VT, float* __restrict__ OUT) {
    __shared__ __align__(16) _Float16 smem[32768];  // dbuf staging; P[128][136] aliases after
    const int tid = threadIdx.x, wave = tid >> 6, lane = tid & 63;
    const int lr = lane & 15, lkg = lane >> 4;
    const int b = blockIdx.x, dblk = blockIdx.y;
    const _Float16* gd = Do + ((size_t)b * LD + dblk * 128) * EMB;
    const _Float16* gq = Qo + (size_t)b * LQ * EMB;

    f32x4 s[2][8];
#pragma unroll
    for (int m = 0; m < 2; ++m)
#pragma unroll
        for (int n = 0; n < 8; ++n) s[m][n] = (f32x4){0.f, 0.f, 0.f, 0.f};

    stage_tile(gd, smem, tid);
    stage_tile(gq, smem + 8192, tid);
    int cur = 0;
    for (int it = 0; it < 12; ++it) {
        __syncthreads();
        if (it < 11) {
            stage_tile(gd + (it + 1) * 64, smem + (cur ^ 1) * 16384, tid);
            stage_tile(gq + (it + 1) * 64, smem + (cur ^ 1) * 16384 + 8192, tid);
        }
        const _Float16* sD = smem + cur * 16384;
        const _Float16* sQ = sD + 8192;
#pragma unroll
        for (int kk = 0; kk < 2; ++kk) {
            const int ch = kk * 4 + lkg;
            f16x8 am[2];
#pragma unroll
            for (int m = 0; m < 2; ++m)
                am[m] = *(const f16x8*)(sD + SWZ(wave * 32 + m * 16 + lr, ch));
#pragma unroll
            for (int n = 0; n < 8; ++n) {
                const f16x8 bq = *(const f16x8*)(sQ + SWZ(n * 16 + lr, ch));
#pragma unroll
                for (int m = 0; m < 2; ++m)
                    s[m][n] = __builtin_amdgcn_mfma_f32_16x16x32_f16(am[m], bq, s[m][n], 0, 0, 0);
            }
        }
        cur ^= 1;
    }
    __syncthreads();  // all staging-buffer reads done before P overwrites smem

    _Float16 (*P)[136] = (_Float16 (*)[136])smem;  // pad 8: 272B stride -> 2-way (free)
    const int crow = lkg * 4;
#pragma unroll
    for (int m = 0; m < 2; ++m) {
#pragma unroll
        for (int r = 0; r < 4; ++r) {
            float mx = -1e30f;
#pragma unroll
            for (int n = 0; n < 8; ++n) mx = fmaxf(mx, s[m][n][r]);
#pragma unroll
            for (int off = 1; off < 16; off <<= 1) mx = fmaxf(mx, __shfl_xor(mx, off));
            float p[8], sum = 0.f;
#pragma unroll
            for (int n = 0; n < 8; ++n) { p[n] = __expf(s[m][n][r] - mx); sum += p[n]; }
#pragma unroll
            for (int off = 1; off < 16; off <<= 1) sum += __shfl_xor(sum, off);
            const float inv = 1.f / sum;
            const int row = wave * 32 + m * 16 + crow + r;
#pragma unroll
            for (int n = 0; n < 8; ++n) P[row][n * 16 + lr] = (_Float16)(p[n] * inv);
        }
    }
    __syncthreads();

    const _Float16* vtb = VT + (size_t)b * EMB * LQ;
#pragma unroll 1
    for (int nc = 0; nc < 6; ++nc) {
        f32x4 o[2][8];
#pragma unroll
        for (int m = 0; m < 2; ++m)
#pragma unroll
            for (int t = 0; t < 8; ++t) o[m][t] = (f32x4){0.f, 0.f, 0.f, 0.f};
#pragma unroll
        for (int ks = 0; ks < 4; ++ks) {
            f16x8 am[2];
#pragma unroll
            for (int m = 0; m < 2; ++m)
                am[m] = *(const f16x8*)(&P[wave * 32 + m * 16 + lr][ks * 32 + lkg * 8]);
#pragma unroll
            for (int t = 0; t < 8; ++t) {
                const f16x8 bv = *(const f16x8*)(vtb + (size_t)(nc * 128 + t * 16 + lr) * LQ + ks * 32 + lkg * 8);
#pragma unroll
                for (int m = 0; m < 2; ++m)
                    o[m][t] = __builtin_amdgcn_mfma_f32_16x16x32_f16(am[m], bv, o[m][t], 0, 0, 0);
            }
        }
#pragma unroll
        for (int t = 0; t < 8; ++t) {
#pragma unroll
            for (int m = 0; m < 2; ++m) {
                const size_t gr = (size_t)b * LD + dblk * 128 + wave * 32 + m * 16 + crow;
                const int e = nc * 128 + t * 16 + lr;
#pragma unroll
                for (int r = 0; r < 4; ++r)
                    OUT[(gr + r) * EMB + e] = o[m][t][r];
            }
        }
    }
}

extern "C" void kernel_launch(void* const* d_in, const int* in_sizes, int n_in,
                              void* d_out, int out_size, void* d_ws, size_t ws_size,
                              hipStream_t stream) {
    const float* doc   = (const float*)d_in[0];   // [32,1024,768]
    const float* query = (const float*)d_in[1];   // [32,128,768]
    const float* W     = (const float*)d_in[2];   // [768,768]
    const float* bias  = (const float*)d_in[3];   // [768]
    float* out = (float*)d_out;                   // [32,1024,768] f32

    const size_t nW  = (size_t)EMB * EMB;        // 589824
    const size_t nVT = (size_t)NB * EMB * LQ;    // 3145728
    const size_t nQo = (size_t)NB * LQ * EMB;    // 3145728
    const size_t nDo = (size_t)NB * LD * EMB;    // 25165824
    const size_t need = (nW + nVT + nQo + nDo) * sizeof(_Float16);  // ~64.1 MB (proven fits)
    if (ws_size < need) return;

    _Float16* W16 = (_Float16*)d_ws;
    _Float16* VT  = W16 + nW;
    _Float16* Qo  = VT + nVT;
    _Float16* Do  = Qo + nQo;

    cvt8_kernel<<<(int)(nW / 8 / 256), 256, 0, stream>>>(W, W16, (int)(nW / 8));
    make_vt_kernel<<<(int)(nVT / 256), 256, 0, stream>>>(query, VT);

    // projections read f32 activations directly (no cvt pass)
    projd_kernel<<<dim3(NB * LQ / 128, EMB / 128), 256, 0, stream>>>(query, W16, bias, Qo);
    projd_kernel<<<dim3(NB * LD / 128, EMB / 128), 256, 0, stream>>>(doc, W16, bias, Do);

    attn128_kernel<<<dim3(NB, LD / 128), 256, 0, stream>>>(Do, Qo, VT, out);
}